// Round 11
// baseline (244.027 us; speedup 1.0000x reference)
//
#include <hip/hip_runtime.h>
#include <stdint.h>

typedef _Float16 f16;
typedef _Float16 half4 __attribute__((ext_vector_type(4)));
typedef _Float16 f16x8 __attribute__((ext_vector_type(8)));
typedef float f32x4 __attribute__((ext_vector_type(4)));

// ---------------- CSR build params: 256-node buckets, bucket-strided ebuf ----------------

#define BKT_SH 8
#define BKT_SZ 256
#define EB 4096
#define BCAP 16384  // per-bucket capacity (uniform-random E=800k over 196 buckets -> max ~4.4k)

struct __attribute__((aligned(16))) G1S { f16 WB[4 * 8 * 64 * 8]; f16 Ah[64 * 136]; };  // 49 KB
struct BinS { int h[256], segs[256], cur[256]; };
struct CsrS { int cnt[256], exc[256], cur2[256], p[256]; };
union __attribute__((aligned(16))) SmemU { G1S g1; BinS bin; CsrS csr; };

// ---------------- CSR device bodies (256 threads) ----------------

// single-pass binning + true-degree histogram (global atomics; deg consumed in phase 2)
__device__ __forceinline__ void dev_binA2(SmemU& sm, const int* __restrict__ src,
                                          const int* __restrict__ dst, int E,
                                          int* __restrict__ bcur, int* __restrict__ deg,
                                          unsigned* __restrict__ ebuf, int bid) {
    int* h = sm.bin.h; int* segs = sm.bin.segs; int* cur = sm.bin.cur;
    int tid = threadIdx.x;
    h[tid] = 0; cur[tid] = 0;
    __syncthreads();
    int base = bid * EB;
    int end = min(base + EB, E);
    for (int i = base + tid; i < end; i += 256) {
        int d = dst[i];
        atomicAdd(&h[d >> BKT_SH], 1);
        atomicAdd(&deg[d], 1);  // true per-node degree (global)
    }
    __syncthreads();
    segs[tid] = h[tid] ? atomicAdd(&bcur[tid], h[tid]) : 0;
    __syncthreads();
    for (int i = base + tid; i < end; i += 256) {
        int d = dst[i];
        int bk = d >> BKT_SH;
        int r = atomicAdd(&cur[bk], 1);
        ebuf[(size_t)bk * BCAP + segs[bk] + r] =
            (unsigned)src[i] | ((unsigned)(d & (BKT_SZ - 1)) << 17);
    }
}

// per-bucket counting sort -> ssorted2 pairs {src, dinv[src]} + row_ptr + dinv
__device__ __forceinline__ void dev_csr2(SmemU& sm, const unsigned* __restrict__ ebuf,
                                         const int* __restrict__ bcur, const int* __restrict__ deg,
                                         int n, int E,
                                         int* __restrict__ row_ptr, float* __restrict__ dinv,
                                         int2* __restrict__ ss2, int b) {
    int* cnt = sm.csr.cnt; int* exc = sm.csr.exc; int* cur2 = sm.csr.cur2; int* p = sm.csr.p;
    int tid = threadIdx.x;
    int v = bcur[tid];
    p[tid] = v;
    __syncthreads();
    for (int o = 1; o < 256; o <<= 1) {
        int t = (tid >= o) ? p[tid - o] : 0;
        __syncthreads();
        p[tid] += t;
        __syncthreads();
    }
    int scnt = bcur[b];
    int s0 = p[b] - scnt;
    __syncthreads();
    if (b == 0 && tid == 0) row_ptr[n] = E;

    const unsigned* eb = &ebuf[(size_t)b * BCAP];
    int d0 = b << BKT_SH;
    int ndl = min(BKT_SZ, n - d0);
    cnt[tid] = 0; cur2[tid] = 0;
    __syncthreads();
    for (int i = tid; i < scnt; i += 256)
        atomicAdd(&cnt[(eb[i] >> 17) & (BKT_SZ - 1)], 1);
    __syncthreads();
    int c = cnt[tid];
    p[tid] = c;
    __syncthreads();
    for (int o = 1; o < 256; o <<= 1) {
        int t = (tid >= o) ? p[tid - o] : 0;
        __syncthreads();
        p[tid] += t;
        __syncthreads();
    }
    int exc_t = p[tid] - c;
    exc[tid] = exc_t;
    if (tid < ndl) {
        row_ptr[d0 + tid] = s0 + exc_t;
        dinv[d0 + tid] = rsqrtf((float)(c + 1));  // +1 self loop (c == deg[d0+tid])
    }
    __syncthreads();
    for (int i = tid; i < scnt; i += 256) {
        unsigned e = eb[i];
        int srcid = (int)(e & 0x1FFFF);
        int dl = (e >> 17) & (BKT_SZ - 1);
        int r = atomicAdd(&cur2[dl], 1);
        // bit-identical to dinv[srcid]: same integer count, same rsqrtf
        float wsrc = rsqrtf((float)(deg[srcid] + 1));
        ss2[s0 + exc[dl] + r] = make_int2(srcid, __float_as_int(wsrc));
    }
}

// GEMM1 body: h1_pre[64 rows of tile][64] = x[.,256] @ W[256,64] -> f16
__device__ __forceinline__ void dev_gemm1(SmemU& sm, const float* __restrict__ x,
                                          const float* __restrict__ W, f16* __restrict__ out,
                                          int n, int tile) {
    f16* WB = sm.g1.WB;
    f16* Ah = sm.g1.Ah;
    int tid = threadIdx.x;
    int row0 = tile * 64;

    for (int i = tid; i < 2048; i += 256) {  // 2048 octets, conflict-free staging
        int m = i & 15, q = (i >> 4) & 3, ks = (i >> 6) & 7, t = i >> 9;
        int col = 16 * t + m;
        int k0 = ks * 32 + q * 8;
        f16x8 v;
#pragma unroll
        for (int j = 0; j < 8; j++) v[j] = (f16)W[(k0 + j) * 64 + col];
        *(f16x8*)&WB[i * 8] = v;
    }

    int lane = tid & 63, w = tid >> 6;
    int m = lane & 15, q = lane >> 4;

    f32x4 acc[4];
#pragma unroll
    for (int t = 0; t < 4; t++) acc[t] = (f32x4){0.f, 0.f, 0.f, 0.f};

    for (int h = 0; h < 2; h++) {
        __syncthreads();
        for (int i = tid; i < 2048; i += 256) {
            int r = i >> 5, k4 = (i & 31) * 4;
            float4 v = {0.f, 0.f, 0.f, 0.f};
            if (row0 + r < n) v = *(const float4*)&x[(size_t)(row0 + r) * 256 + 128 * h + k4];
            half4 hv;
            hv.x = (f16)v.x; hv.y = (f16)v.y; hv.z = (f16)v.z; hv.w = (f16)v.w;
            *(half4*)&Ah[r * 136 + k4] = hv;
        }
        __syncthreads();
#pragma unroll
        for (int ksl = 0; ksl < 4; ksl++) {
            int ks = 4 * h + ksl;
            f16x8 a = *(const f16x8*)&Ah[(16 * w + m) * 136 + 32 * ksl + 8 * q];
#pragma unroll
            for (int t = 0; t < 4; t++) {
                f16x8 b = *(const f16x8*)&WB[((t * 8 + ks) * 64 + lane) * 8];
                acc[t] = __builtin_amdgcn_mfma_f32_16x16x32_f16(a, b, acc[t], 0, 0, 0);
            }
        }
    }

#pragma unroll
    for (int t = 0; t < 4; t++) {
#pragma unroll
        for (int r = 0; r < 4; r++) {
            int gr = row0 + 16 * w + 4 * q + r;
            if (gr < n) out[(size_t)gr * 64 + 16 * t + m] = (f16)acc[t][r];
        }
    }
}

// ---------------- phase kernels: CSR stage (blocks [0,nA)) + gemm1 slice ---------

__global__ __launch_bounds__(256) void k_p1(const int* __restrict__ src, const int* __restrict__ dst,
                                            int E, int* __restrict__ bcur, int* __restrict__ deg,
                                            unsigned* __restrict__ ebuf,
                                            const float* __restrict__ x, const float* __restrict__ W,
                                            f16* __restrict__ out, int n, int nA, int tile0) {
    __shared__ SmemU sm;
    if ((int)blockIdx.x < nA) dev_binA2(sm, src, dst, E, bcur, deg, ebuf, blockIdx.x);
    else dev_gemm1(sm, x, W, out, n, tile0 + (int)blockIdx.x - nA);
}

__global__ __launch_bounds__(256) void k_p2(const unsigned* __restrict__ ebuf,
                                            const int* __restrict__ bcur, const int* __restrict__ deg,
                                            int n, int E,
                                            int* __restrict__ row_ptr, float* __restrict__ dinv,
                                            int2* __restrict__ ss2,
                                            const float* __restrict__ x, const float* __restrict__ W,
                                            f16* __restrict__ out, int nA, int tile0) {
    __shared__ SmemU sm;
    if ((int)blockIdx.x < nA) dev_csr2(sm, ebuf, bcur, deg, n, E, row_ptr, dinv, ss2, blockIdx.x);
    else dev_gemm1(sm, x, W, out, n, tile0 + (int)blockIdx.x - nA);
}

// ---------------- gather macro body (16-lane group, 8-deep unroll) ----------------
// ssorted2 entry = {src, w=dinv[src]}: one coalesced 8B load per lane; no random dinv gather.

#define GCN_GATHER(hpre, d, fg, AX, AY, AZ, AW, DD)                                     \
    {                                                                                   \
        half4 hs_ = *(const half4*)&hpre[(size_t)(d) * 64 + 4 * (fg)];                  \
        AX = DD * (float)hs_.x; AY = DD * (float)hs_.y;                                 \
        AZ = DD * (float)hs_.z; AW = DD * (float)hs_.w;                                 \
        int s0_ = row_ptr[d], s1_ = row_ptr[(d) + 1];                                   \
        for (int base_ = s0_; base_ < s1_; base_ += 16) {                               \
            int j_ = base_ + (fg);                                                      \
            int slv_ = 0;                                                               \
            float wl_ = 0.f;                                                            \
            if (j_ < s1_) { int2 ev_ = ss2[j_]; slv_ = ev_.x; wl_ = __int_as_float(ev_.y); } \
            int cnt_ = min(16, s1_ - base_);                                            \
            for (int i_ = 0; i_ < cnt_; i_ += 8) {                                      \
                int a0 = __shfl(slv_, i_ + 0, 16), a1 = __shfl(slv_, i_ + 1, 16);       \
                int a2 = __shfl(slv_, i_ + 2, 16), a3 = __shfl(slv_, i_ + 3, 16);       \
                int a4 = __shfl(slv_, i_ + 4, 16), a5 = __shfl(slv_, i_ + 5, 16);       \
                int a6 = __shfl(slv_, i_ + 6, 16), a7 = __shfl(slv_, i_ + 7, 16);       \
                float w0 = __shfl(wl_, i_ + 0, 16), w1 = __shfl(wl_, i_ + 1, 16);       \
                float w2 = __shfl(wl_, i_ + 2, 16), w3 = __shfl(wl_, i_ + 3, 16);       \
                float w4 = __shfl(wl_, i_ + 4, 16), w5 = __shfl(wl_, i_ + 5, 16);       \
                float w6 = __shfl(wl_, i_ + 6, 16), w7 = __shfl(wl_, i_ + 7, 16);       \
                half4 h0 = *(const half4*)&hpre[(size_t)a0 * 64 + 4 * (fg)];            \
                half4 h1 = *(const half4*)&hpre[(size_t)a1 * 64 + 4 * (fg)];            \
                half4 h2 = *(const half4*)&hpre[(size_t)a2 * 64 + 4 * (fg)];            \
                half4 h3 = *(const half4*)&hpre[(size_t)a3 * 64 + 4 * (fg)];            \
                half4 h4 = *(const half4*)&hpre[(size_t)a4 * 64 + 4 * (fg)];            \
                half4 h5 = *(const half4*)&hpre[(size_t)a5 * 64 + 4 * (fg)];            \
                half4 h6 = *(const half4*)&hpre[(size_t)a6 * 64 + 4 * (fg)];            \
                half4 h7 = *(const half4*)&hpre[(size_t)a7 * 64 + 4 * (fg)];            \
                AX += w0 * (float)h0.x; AY += w0 * (float)h0.y;                         \
                AZ += w0 * (float)h0.z; AW += w0 * (float)h0.w;                         \
                AX += w1 * (float)h1.x; AY += w1 * (float)h1.y;                         \
                AZ += w1 * (float)h1.z; AW += w1 * (float)h1.w;                         \
                AX += w2 * (float)h2.x; AY += w2 * (float)h2.y;                         \
                AZ += w2 * (float)h2.z; AW += w2 * (float)h2.w;                         \
                AX += w3 * (float)h3.x; AY += w3 * (float)h3.y;                         \
                AZ += w3 * (float)h3.z; AW += w3 * (float)h3.w;                         \
                AX += w4 * (float)h4.x; AY += w4 * (float)h4.y;                         \
                AZ += w4 * (float)h4.z; AW += w4 * (float)h4.w;                         \
                AX += w5 * (float)h5.x; AY += w5 * (float)h5.y;                         \
                AZ += w5 * (float)h5.z; AW += w5 * (float)h5.w;                         \
                AX += w6 * (float)h6.x; AY += w6 * (float)h6.y;                         \
                AZ += w6 * (float)h6.z; AW += w6 * (float)h6.w;                         \
                AX += w7 * (float)h7.x; AY += w7 * (float)h7.y;                         \
                AZ += w7 * (float)h7.z; AW += w7 * (float)h7.w;                         \
            }                                                                           \
        }                                                                               \
    }

// ---------------- fused prop1 + middle (MFMA): 64 nodes per block, 8 waves ----------------

__global__ __launch_bounds__(512, 6) void k_midf(const f16* __restrict__ h1pre,
                                                 const int* __restrict__ row_ptr,
                                                 const int2* __restrict__ ss2,
                                                 const float* __restrict__ dinv,
                                                 const float* __restrict__ benc,
                                                 const float* __restrict__ Wz, const float* __restrict__ bz,
                                                 const float* __restrict__ Wd, const float* __restrict__ bd,
                                                 const float* __restrict__ Wc, const float* __restrict__ bc,
                                                 f16* __restrict__ hd_ws,
                                                 float* __restrict__ z_out, float* __restrict__ pred_out,
                                                 int n) {
    __shared__ __attribute__((aligned(16))) f16 Ah[64 * 72];
    __shared__ __attribute__((aligned(16))) f16 Zh[64 * 40];
    __shared__ __attribute__((aligned(16))) f16 WzB[2 * 2 * 64 * 8];
    __shared__ __attribute__((aligned(16))) f16 WdB[4 * 64 * 8];
    __shared__ float Wcs[32 * 4];
    __shared__ float bzs[32], bds[64], bcs[4], bes[64];
    int tid = threadIdx.x;
    int row0 = blockIdx.x * 64;

    if (tid < 256) {
        int i = tid;
        int m = i & 15, q = (i >> 4) & 3, ks = (i >> 6) & 1, t = i >> 7;
        int col = 16 * t + m;
        int k0 = ks * 32 + q * 8;
        f16x8 v;
#pragma unroll
        for (int j = 0; j < 8; j++) v[j] = (f16)Wz[(k0 + j) * 32 + col];
        *(f16x8*)&WzB[i * 8] = v;
    } else {
        int i = tid - 256;
        int m = i & 15, q = (i >> 4) & 3, t = i >> 6;
        int col = 16 * t + m;
        int k0 = q * 8;
        f16x8 v;
#pragma unroll
        for (int j = 0; j < 8; j++) v[j] = (f16)Wd[(k0 + j) * 64 + col];
        *(f16x8*)&WdB[i * 8] = v;
    }
    if (tid < 96) Wcs[(tid / 3) * 4 + (tid % 3)] = Wc[tid];
    if (tid < 32) bzs[tid] = bz[tid];
    if (tid < 64) bds[tid] = bd[tid];
    if (tid < 3)  bcs[tid] = bc[tid];
    if (tid < 64) bes[tid] = benc[tid];
    __syncthreads();  // bes ready before gather

    int lane = tid & 63, wid = tid >> 6;  // wid 0..7
    int g = lane >> 4, fg = lane & 15;

    // gather phase: 32 node-slots per round, 2 rounds
    for (int r = 0; r < 2; r++) {
        int no = 32 * r + 4 * wid + g;
        int d = row0 + no;
        float vx = 0.f, vy = 0.f, vz = 0.f, vw = 0.f;
        if (d < n) {
            float dd = dinv[d];
            float ax, ay, az, aw;
            GCN_GATHER(h1pre, d, fg, ax, ay, az, aw, dd);
            float4 b = *(float4*)&bes[4 * fg];
            vx = fmaxf(dd * ax + b.x, 0.f); vy = fmaxf(dd * ay + b.y, 0.f);
            vz = fmaxf(dd * az + b.z, 0.f); vw = fmaxf(dd * aw + b.w, 0.f);
        }
        half4 hv;
        hv.x = (f16)vx; hv.y = (f16)vy; hv.z = (f16)vz; hv.w = (f16)vw;
        *(half4*)&Ah[no * 72 + 4 * fg] = hv;
    }
    __syncthreads();

    int m = lane & 15, q = lane >> 4;
    int rowg = wid & 3, tsel = wid >> 2;

    // z = Ah @ Wz + bz : wave handles t = tsel
    f32x4 za = (f32x4){0.f, 0.f, 0.f, 0.f};
#pragma unroll
    for (int ks = 0; ks < 2; ks++) {
        f16x8 a = *(const f16x8*)&Ah[(16 * rowg + m) * 72 + 32 * ks + 8 * q];
        f16x8 b = *(const f16x8*)&WzB[((tsel * 2 + ks) * 64 + lane) * 8];
        za = __builtin_amdgcn_mfma_f32_16x16x32_f16(a, b, za, 0, 0, 0);
    }
    {
        float bj = bzs[16 * tsel + m];
#pragma unroll
        for (int r = 0; r < 4; r++) {
            int node = 16 * rowg + 4 * q + r;
            float zv = za[r] + bj;
            Zh[node * 40 + 16 * tsel + m] = (f16)zv;
            if (row0 + node < n) z_out[(size_t)(row0 + node) * 32 + 16 * tsel + m] = zv;
        }
    }
    __syncthreads();

    // hd = relu(Zh @ Wd + bd) : wave handles t = 2*tsel + {0,1}
    f16x8 a2 = *(const f16x8*)&Zh[(16 * rowg + m) * 40 + 8 * q];
#pragma unroll
    for (int tt = 0; tt < 2; tt++) {
        int t = 2 * tsel + tt;
        f32x4 zero = (f32x4){0.f, 0.f, 0.f, 0.f};
        f16x8 b = *(const f16x8*)&WdB[(t * 64 + lane) * 8];
        f32x4 hb = __builtin_amdgcn_mfma_f32_16x16x32_f16(a2, b, zero, 0, 0, 0);
        float bf = bds[16 * t + m];
#pragma unroll
        for (int r = 0; r < 4; r++) {
            int node = 16 * rowg + 4 * q + r;
            if (row0 + node < n)
                hd_ws[(size_t)(row0 + node) * 64 + 16 * t + m] = (f16)fmaxf(hb[r] + bf, 0.f);
        }
    }

    if (tid < 64) {
        int node = tid;
        float pa = bcs[0], pb = bcs[1], pc = bcs[2];
        for (int k = 0; k < 32; k++) {
            float zv = (float)Zh[node * 40 + k];
            pa += zv * Wcs[k * 4 + 0];
            pb += zv * Wcs[k * 4 + 1];
            pc += zv * Wcs[k * 4 + 2];
        }
        if (row0 + node < n) {
            pred_out[(size_t)(row0 + node) * 3 + 0] = pa;
            pred_out[(size_t)(row0 + node) * 3 + 1] = pb;
            pred_out[(size_t)(row0 + node) * 3 + 2] = pc;
        }
    }
}

// ---------------- fused prop2 + GEMM5: 64 nodes per block, 8 waves, full-W staged ------

__global__ __launch_bounds__(512, 6) void k_decf(const f16* __restrict__ hd,
                                                 const int* __restrict__ row_ptr,
                                                 const int2* __restrict__ ss2,
                                                 const float* __restrict__ dinv,
                                                 const float* __restrict__ W,
                                                 const float* __restrict__ bias,
                                                 float* __restrict__ out, int n) {
    __shared__ __attribute__((aligned(16))) f16 WB[16 * 2 * 64 * 8];  // 32 KB
    __shared__ __attribute__((aligned(16))) f16 Ah[64 * 72];          // 9 KB
    __shared__ float bs[256];
    int tid = threadIdx.x;
    int row0 = blockIdx.x * 64;

    if (tid < 256) bs[tid] = bias[tid];

    for (int i = tid; i < 2048; i += 512) {
        int m = i & 15, q = (i >> 4) & 3, ks = (i >> 6) & 1, t = i >> 7;
        int col = 16 * t + m;
        int k0 = ks * 32 + q * 8;
        f16x8 v;
#pragma unroll
        for (int j = 0; j < 8; j++) v[j] = (f16)W[(k0 + j) * 256 + col];
        *(f16x8*)&WB[i * 8] = v;
    }

    int lane = tid & 63, wid = tid >> 6;  // wid 0..7
    int g = lane >> 4, fg = lane & 15;

    // gather phase: P(hd) rows -> Ah ; 32 node-slots per round, 2 rounds
    for (int r = 0; r < 2; r++) {
        int no = 32 * r + 4 * wid + g;
        int d = row0 + no;
        float vx = 0.f, vy = 0.f, vz = 0.f, vw = 0.f;
        if (d < n) {
            float dd = dinv[d];
            float ax, ay, az, aw;
            GCN_GATHER(hd, d, fg, ax, ay, az, aw, dd);
            vx = dd * ax; vy = dd * ay; vz = dd * az; vw = dd * aw;
        }
        half4 hv;
        hv.x = (f16)vx; hv.y = (f16)vy; hv.z = (f16)vz; hv.w = (f16)vw;
        *(half4*)&Ah[no * 72 + 4 * fg] = hv;
    }
    __syncthreads();

    int m = lane & 15, q = lane >> 4;
    int rowg = wid & 3, th = wid >> 2;

    f16x8 a0 = *(const f16x8*)&Ah[(16 * rowg + m) * 72 + 0 + 8 * q];
    f16x8 a1 = *(const f16x8*)&Ah[(16 * rowg + m) * 72 + 32 + 8 * q];

    int gr0 = row0 + 16 * rowg + 4 * q;
    bool full = (gr0 + 3 < n);
#pragma unroll 4
    for (int tl = 0; tl < 8; tl++) {
        int t = 8 * th + tl;
        f32x4 acc = (f32x4){0.f, 0.f, 0.f, 0.f};
        f16x8 b0 = *(const f16x8*)&WB[((t * 2 + 0) * 64 + lane) * 8];
        acc = __builtin_amdgcn_mfma_f32_16x16x32_f16(a0, b0, acc, 0, 0, 0);
        f16x8 b1 = *(const f16x8*)&WB[((t * 2 + 1) * 64 + lane) * 8];
        acc = __builtin_amdgcn_mfma_f32_16x16x32_f16(a1, b1, acc, 0, 0, 0);
        float bf = bs[16 * t + m];
        if (full) {
#pragma unroll
            for (int r = 0; r < 4; r++)
                out[(size_t)(gr0 + r) * 256 + 16 * t + m] = acc[r] + bf;
        } else {
#pragma unroll
            for (int r = 0; r < 4; r++)
                if (gr0 + r < n) out[(size_t)(gr0 + r) * 256 + 16 * t + m] = acc[r] + bf;
        }
    }
}

// ---------------- launch ----------------

extern "C" void kernel_launch(void* const* d_in, const int* in_sizes, int n_in,
                              void* d_out, int out_size, void* d_ws, size_t ws_size,
                              hipStream_t stream) {
    const float* x    = (const float*)d_in[0];
    const int*   ei   = (const int*)d_in[1];
    const float* Wenc = (const float*)d_in[3];
    const float* benc = (const float*)d_in[4];
    const float* Wz   = (const float*)d_in[5];
    const float* bz   = (const float*)d_in[6];
    const float* Wd   = (const float*)d_in[7];
    const float* bd   = (const float*)d_in[8];
    const float* Wdec = (const float*)d_in[9];
    const float* bdec = (const float*)d_in[10];
    const float* Wc   = (const float*)d_in[11];
    const float* bc   = (const float*)d_in[12];

    int n = in_sizes[0] / 256;
    int E = in_sizes[1] / 2;
    const int* src = ei;
    const int* dst = ei + E;

    int nbk = (n + BKT_SZ - 1) >> BKT_SH;
    int nbin = (E + EB - 1) / EB;

    char* w = (char*)d_ws;
    size_t off = 0;
    auto alloc = [&](size_t bytes) {
        void* p = w + off;
        off = (off + bytes + 255) & ~(size_t)255;
        return p;
    };
    int*      row_ptr = (int*)alloc(sizeof(int) * (n + 1));
    int2*     ss2     = (int2*)alloc(sizeof(int2) * E);
    unsigned* ebuf    = (unsigned*)alloc(sizeof(unsigned) * (size_t)nbk * BCAP);
    float*    dinv    = (float*)alloc(sizeof(float) * n);
    int*      cnts    = (int*)alloc(sizeof(int) * (256 + n));  // bcur[256] + deg[n]
    f16*      bufA    = (f16*)alloc(sizeof(f16) * (size_t)n * 64);  // h1pre
    f16*      bufB    = (f16*)alloc(sizeof(f16) * (size_t)n * 64);  // hd
    (void)ws_size; (void)n_in; (void)out_size;

    int* bcur = cnts;
    int* deg  = cnts + 256;

    float* out_xr = (float*)d_out;
    float* out_z  = out_xr + (size_t)n * 256;
    float* out_p  = out_z + (size_t)n * 32;

    int tiles = (n + 63) / 64;
    int th = tiles / 2;

    hipMemsetAsync(cnts, 0, sizeof(int) * (256 + n), stream);

    // phase 1: binning + deg histogram || gemm1 tiles [0, th)
    k_p1<<<dim3(nbin + th), dim3(256), 0, stream>>>(src, dst, E, bcur, deg, ebuf,
                                                    x, Wenc, bufA, n, nbin, 0);
    // phase 2: per-bucket CSR (pairs) || gemm1 tiles [th, tiles)
    k_p2<<<dim3(nbk + (tiles - th)), dim3(256), 0, stream>>>(ebuf, bcur, deg, n, E,
                                                             row_ptr, dinv, ss2,
                                                             x, Wenc, bufA, nbk, th);

    // fused prop1 + middle: z (out), pred (out), hd -> bufB
    k_midf<<<dim3(tiles), dim3(512), 0, stream>>>(bufA, row_ptr, ss2, dinv, benc,
                                                  Wz, bz, Wd, bd, Wc, bc,
                                                  bufB, out_z, out_p, n);

    // fused prop2 + decoder GEMM: x_recon = P(bufB) @ W_dec + b_dec
    k_decf<<<dim3(tiles), dim3(512), 0, stream>>>(bufB, row_ptr, ss2, dinv,
                                                  Wdec, bdec, out_xr, n);
}

// Round 12
// 212.781 us; speedup vs baseline: 1.1468x; 1.1468x over previous
//
#include <hip/hip_runtime.h>
#include <stdint.h>

typedef _Float16 f16;
typedef _Float16 half4 __attribute__((ext_vector_type(4)));
typedef _Float16 f16x8 __attribute__((ext_vector_type(8)));
typedef float f32x4 __attribute__((ext_vector_type(4)));

// ---------------- CSR build params: 256-node buckets, bucket-strided ebuf ----------------

#define BKT_SH 8
#define BKT_SZ 256
#define EB 4096
#define BCAP 16384  // per-bucket capacity (uniform-random E=800k over 196 buckets -> max ~4.4k)

struct __attribute__((aligned(16))) G1S { f16 WB[4 * 8 * 64 * 8]; f16 Ah[64 * 136]; };  // 49 KB
struct BinS { int h[256], segs[256], cur[256]; };
struct CsrS { int cnt[256], exc[256], cur2[256], p[256]; };
union __attribute__((aligned(16))) SmemU { G1S g1; BinS bin; CsrS csr; };

// ---------------- CSR device bodies (256 threads) ----------------

__device__ __forceinline__ void dev_binA2(SmemU& sm, const int* __restrict__ src,
                                          const int* __restrict__ dst, int E,
                                          int* __restrict__ bcur, unsigned* __restrict__ ebuf,
                                          int bid) {
    int* h = sm.bin.h; int* segs = sm.bin.segs; int* cur = sm.bin.cur;
    int tid = threadIdx.x;
    h[tid] = 0; cur[tid] = 0;
    __syncthreads();
    int base = bid * EB;
    int end = min(base + EB, E);
    for (int i = base + tid; i < end; i += 256) atomicAdd(&h[dst[i] >> BKT_SH], 1);
    __syncthreads();
    segs[tid] = h[tid] ? atomicAdd(&bcur[tid], h[tid]) : 0;
    __syncthreads();
    for (int i = base + tid; i < end; i += 256) {
        int d = dst[i];
        int bk = d >> BKT_SH;
        int r = atomicAdd(&cur[bk], 1);
        ebuf[(size_t)bk * BCAP + segs[bk] + r] =
            (unsigned)src[i] | ((unsigned)(d & (BKT_SZ - 1)) << 17);
    }
}

__device__ __forceinline__ void dev_csr2(SmemU& sm, const unsigned* __restrict__ ebuf,
                                         const int* __restrict__ bcur, int n, int E,
                                         int* __restrict__ row_ptr, float* __restrict__ dinv,
                                         int* __restrict__ ssorted, int b) {
    int* cnt = sm.csr.cnt; int* exc = sm.csr.exc; int* cur2 = sm.csr.cur2; int* p = sm.csr.p;
    int tid = threadIdx.x;
    int v = bcur[tid];
    p[tid] = v;
    __syncthreads();
    for (int o = 1; o < 256; o <<= 1) {
        int t = (tid >= o) ? p[tid - o] : 0;
        __syncthreads();
        p[tid] += t;
        __syncthreads();
    }
    int scnt = bcur[b];
    int s0 = p[b] - scnt;
    __syncthreads();
    if (b == 0 && tid == 0) row_ptr[n] = E;

    const unsigned* eb = &ebuf[(size_t)b * BCAP];
    int d0 = b << BKT_SH;
    int ndl = min(BKT_SZ, n - d0);
    cnt[tid] = 0; cur2[tid] = 0;
    __syncthreads();
    for (int i = tid; i < scnt; i += 256)
        atomicAdd(&cnt[(eb[i] >> 17) & (BKT_SZ - 1)], 1);
    __syncthreads();
    int c = cnt[tid];
    p[tid] = c;
    __syncthreads();
    for (int o = 1; o < 256; o <<= 1) {
        int t = (tid >= o) ? p[tid - o] : 0;
        __syncthreads();
        p[tid] += t;
        __syncthreads();
    }
    int exc_t = p[tid] - c;
    exc[tid] = exc_t;
    if (tid < ndl) {
        row_ptr[d0 + tid] = s0 + exc_t;
        dinv[d0 + tid] = rsqrtf((float)(c + 1));  // +1 self loop
    }
    __syncthreads();
    for (int i = tid; i < scnt; i += 256) {
        unsigned e = eb[i];
        int dl = (e >> 17) & (BKT_SZ - 1);
        int r = atomicAdd(&cur2[dl], 1);
        ssorted[s0 + exc[dl] + r] = (int)(e & 0x1FFFF);
    }
}

// GEMM1 body: h1_pre[64 rows of tile][64] = x[.,256] @ W[256,64] -> f16
__device__ __forceinline__ void dev_gemm1(SmemU& sm, const float* __restrict__ x,
                                          const float* __restrict__ W, f16* __restrict__ out,
                                          int n, int tile) {
    f16* WB = sm.g1.WB;
    f16* Ah = sm.g1.Ah;
    int tid = threadIdx.x;
    int row0 = tile * 64;

    for (int i = tid; i < 2048; i += 256) {  // 2048 octets, conflict-free staging
        int m = i & 15, q = (i >> 4) & 3, ks = (i >> 6) & 7, t = i >> 9;
        int col = 16 * t + m;
        int k0 = ks * 32 + q * 8;
        f16x8 v;
#pragma unroll
        for (int j = 0; j < 8; j++) v[j] = (f16)W[(k0 + j) * 64 + col];
        *(f16x8*)&WB[i * 8] = v;
    }

    int lane = tid & 63, w = tid >> 6;
    int m = lane & 15, q = lane >> 4;

    f32x4 acc[4];
#pragma unroll
    for (int t = 0; t < 4; t++) acc[t] = (f32x4){0.f, 0.f, 0.f, 0.f};

    for (int h = 0; h < 2; h++) {
        __syncthreads();
        for (int i = tid; i < 2048; i += 256) {
            int r = i >> 5, k4 = (i & 31) * 4;
            float4 v = {0.f, 0.f, 0.f, 0.f};
            if (row0 + r < n) v = *(const float4*)&x[(size_t)(row0 + r) * 256 + 128 * h + k4];
            half4 hv;
            hv.x = (f16)v.x; hv.y = (f16)v.y; hv.z = (f16)v.z; hv.w = (f16)v.w;
            *(half4*)&Ah[r * 136 + k4] = hv;
        }
        __syncthreads();
#pragma unroll
        for (int ksl = 0; ksl < 4; ksl++) {
            int ks = 4 * h + ksl;
            f16x8 a = *(const f16x8*)&Ah[(16 * w + m) * 136 + 32 * ksl + 8 * q];
#pragma unroll
            for (int t = 0; t < 4; t++) {
                f16x8 b = *(const f16x8*)&WB[((t * 8 + ks) * 64 + lane) * 8];
                acc[t] = __builtin_amdgcn_mfma_f32_16x16x32_f16(a, b, acc[t], 0, 0, 0);
            }
        }
    }

#pragma unroll
    for (int t = 0; t < 4; t++) {
#pragma unroll
        for (int r = 0; r < 4; r++) {
            int gr = row0 + 16 * w + 4 * q + r;
            if (gr < n) out[(size_t)gr * 64 + 16 * t + m] = (f16)acc[t][r];
        }
    }
}

// ---------------- phase kernels: CSR stage (blocks [0,nA)) + gemm1 slice ---------

__global__ __launch_bounds__(256) void k_p1(const int* __restrict__ src, const int* __restrict__ dst,
                                            int E, int* __restrict__ bcur, unsigned* __restrict__ ebuf,
                                            const float* __restrict__ x, const float* __restrict__ W,
                                            f16* __restrict__ out, int n, int nA, int tile0) {
    __shared__ SmemU sm;
    if ((int)blockIdx.x < nA) dev_binA2(sm, src, dst, E, bcur, ebuf, blockIdx.x);
    else dev_gemm1(sm, x, W, out, n, tile0 + (int)blockIdx.x - nA);
}

__global__ __launch_bounds__(256) void k_p2(const unsigned* __restrict__ ebuf,
                                            const int* __restrict__ bcur, int n, int E,
                                            int* __restrict__ row_ptr, float* __restrict__ dinv,
                                            int* __restrict__ ssorted,
                                            const float* __restrict__ x, const float* __restrict__ W,
                                            f16* __restrict__ out, int nA, int tile0) {
    __shared__ SmemU sm;
    if ((int)blockIdx.x < nA) dev_csr2(sm, ebuf, bcur, n, E, row_ptr, dinv, ssorted, blockIdx.x);
    else dev_gemm1(sm, x, W, out, n, tile0 + (int)blockIdx.x - nA);
}

// ---------------- gather macro body (16-lane group, 8-deep unroll) ----------------

#define GCN_GATHER(hpre, d, fg, AX, AY, AZ, AW, DD)                                     \
    {                                                                                   \
        half4 hs_ = *(const half4*)&hpre[(size_t)(d) * 64 + 4 * (fg)];                  \
        AX = DD * (float)hs_.x; AY = DD * (float)hs_.y;                                 \
        AZ = DD * (float)hs_.z; AW = DD * (float)hs_.w;                                 \
        int s0_ = row_ptr[d], s1_ = row_ptr[(d) + 1];                                   \
        for (int base_ = s0_; base_ < s1_; base_ += 16) {                               \
            int j_ = base_ + (fg);                                                      \
            int slv_ = 0;                                                               \
            float wl_ = 0.f;                                                            \
            if (j_ < s1_) { slv_ = ssorted[j_]; wl_ = dinv[slv_]; }                     \
            int cnt_ = min(16, s1_ - base_);                                            \
            for (int i_ = 0; i_ < cnt_; i_ += 8) {                                      \
                int a0 = __shfl(slv_, i_ + 0, 16), a1 = __shfl(slv_, i_ + 1, 16);       \
                int a2 = __shfl(slv_, i_ + 2, 16), a3 = __shfl(slv_, i_ + 3, 16);       \
                int a4 = __shfl(slv_, i_ + 4, 16), a5 = __shfl(slv_, i_ + 5, 16);       \
                int a6 = __shfl(slv_, i_ + 6, 16), a7 = __shfl(slv_, i_ + 7, 16);       \
                float w0 = __shfl(wl_, i_ + 0, 16), w1 = __shfl(wl_, i_ + 1, 16);       \
                float w2 = __shfl(wl_, i_ + 2, 16), w3 = __shfl(wl_, i_ + 3, 16);       \
                float w4 = __shfl(wl_, i_ + 4, 16), w5 = __shfl(wl_, i_ + 5, 16);       \
                float w6 = __shfl(wl_, i_ + 6, 16), w7 = __shfl(wl_, i_ + 7, 16);       \
                half4 h0 = *(const half4*)&hpre[(size_t)a0 * 64 + 4 * (fg)];            \
                half4 h1 = *(const half4*)&hpre[(size_t)a1 * 64 + 4 * (fg)];            \
                half4 h2 = *(const half4*)&hpre[(size_t)a2 * 64 + 4 * (fg)];            \
                half4 h3 = *(const half4*)&hpre[(size_t)a3 * 64 + 4 * (fg)];            \
                half4 h4 = *(const half4*)&hpre[(size_t)a4 * 64 + 4 * (fg)];            \
                half4 h5 = *(const half4*)&hpre[(size_t)a5 * 64 + 4 * (fg)];            \
                half4 h6 = *(const half4*)&hpre[(size_t)a6 * 64 + 4 * (fg)];            \
                half4 h7 = *(const half4*)&hpre[(size_t)a7 * 64 + 4 * (fg)];            \
                AX += w0 * (float)h0.x; AY += w0 * (float)h0.y;                         \
                AZ += w0 * (float)h0.z; AW += w0 * (float)h0.w;                         \
                AX += w1 * (float)h1.x; AY += w1 * (float)h1.y;                         \
                AZ += w1 * (float)h1.z; AW += w1 * (float)h1.w;                         \
                AX += w2 * (float)h2.x; AY += w2 * (float)h2.y;                         \
                AZ += w2 * (float)h2.z; AW += w2 * (float)h2.w;                         \
                AX += w3 * (float)h3.x; AY += w3 * (float)h3.y;                         \
                AZ += w3 * (float)h3.z; AW += w3 * (float)h3.w;                         \
                AX += w4 * (float)h4.x; AY += w4 * (float)h4.y;                         \
                AZ += w4 * (float)h4.z; AW += w4 * (float)h4.w;                         \
                AX += w5 * (float)h5.x; AY += w5 * (float)h5.y;                         \
                AZ += w5 * (float)h5.z; AW += w5 * (float)h5.w;                         \
                AX += w6 * (float)h6.x; AY += w6 * (float)h6.y;                         \
                AZ += w6 * (float)h6.z; AW += w6 * (float)h6.w;                         \
                AX += w7 * (float)h7.x; AY += w7 * (float)h7.y;                         \
                AZ += w7 * (float)h7.z; AW += w7 * (float)h7.w;                         \
            }                                                                           \
        }                                                                               \
    }

// ---------------- fused prop1 + middle (MFMA): 64 nodes per block, 8 waves ----------------

__global__ __launch_bounds__(512, 6) void k_midf(const f16* __restrict__ h1pre,
                                                 const int* __restrict__ row_ptr,
                                                 const int* __restrict__ ssorted,
                                                 const float* __restrict__ dinv,
                                                 const float* __restrict__ benc,
                                                 const float* __restrict__ Wz, const float* __restrict__ bz,
                                                 const float* __restrict__ Wd, const float* __restrict__ bd,
                                                 const float* __restrict__ Wc, const float* __restrict__ bc,
                                                 f16* __restrict__ hd_ws,
                                                 float* __restrict__ z_out, float* __restrict__ pred_out,
                                                 int n) {
    __shared__ __attribute__((aligned(16))) f16 Ah[64 * 72];
    __shared__ __attribute__((aligned(16))) f16 Zh[64 * 40];
    __shared__ __attribute__((aligned(16))) f16 WzB[2 * 2 * 64 * 8];
    __shared__ __attribute__((aligned(16))) f16 WdB[4 * 64 * 8];
    __shared__ float Wcs[32 * 4];
    __shared__ float bzs[32], bds[64], bcs[4], bes[64];
    int tid = threadIdx.x;
    int row0 = blockIdx.x * 64;

    if (tid < 256) {
        int i = tid;
        int m = i & 15, q = (i >> 4) & 3, ks = (i >> 6) & 1, t = i >> 7;
        int col = 16 * t + m;
        int k0 = ks * 32 + q * 8;
        f16x8 v;
#pragma unroll
        for (int j = 0; j < 8; j++) v[j] = (f16)Wz[(k0 + j) * 32 + col];
        *(f16x8*)&WzB[i * 8] = v;
    } else {
        int i = tid - 256;
        int m = i & 15, q = (i >> 4) & 3, t = i >> 6;
        int col = 16 * t + m;
        int k0 = q * 8;
        f16x8 v;
#pragma unroll
        for (int j = 0; j < 8; j++) v[j] = (f16)Wd[(k0 + j) * 64 + col];
        *(f16x8*)&WdB[i * 8] = v;
    }
    if (tid < 96) Wcs[(tid / 3) * 4 + (tid % 3)] = Wc[tid];
    if (tid < 32) bzs[tid] = bz[tid];
    if (tid < 64) bds[tid] = bd[tid];
    if (tid < 3)  bcs[tid] = bc[tid];
    if (tid < 64) bes[tid] = benc[tid];
    __syncthreads();  // bes ready before gather

    int lane = tid & 63, wid = tid >> 6;  // wid 0..7
    int g = lane >> 4, fg = lane & 15;

    // gather phase: 32 node-slots per round, 2 rounds
    for (int r = 0; r < 2; r++) {
        int no = 32 * r + 4 * wid + g;
        int d = row0 + no;
        float vx = 0.f, vy = 0.f, vz = 0.f, vw = 0.f;
        if (d < n) {
            float dd = dinv[d];
            float ax, ay, az, aw;
            GCN_GATHER(h1pre, d, fg, ax, ay, az, aw, dd);
            float4 b = *(float4*)&bes[4 * fg];
            vx = fmaxf(dd * ax + b.x, 0.f); vy = fmaxf(dd * ay + b.y, 0.f);
            vz = fmaxf(dd * az + b.z, 0.f); vw = fmaxf(dd * aw + b.w, 0.f);
        }
        half4 hv;
        hv.x = (f16)vx; hv.y = (f16)vy; hv.z = (f16)vz; hv.w = (f16)vw;
        *(half4*)&Ah[no * 72 + 4 * fg] = hv;
    }
    __syncthreads();

    int m = lane & 15, q = lane >> 4;
    int rowg = wid & 3, tsel = wid >> 2;

    // z = Ah @ Wz + bz : wave handles t = tsel
    __builtin_amdgcn_s_setprio(1);
    f32x4 za = (f32x4){0.f, 0.f, 0.f, 0.f};
#pragma unroll
    for (int ks = 0; ks < 2; ks++) {
        f16x8 a = *(const f16x8*)&Ah[(16 * rowg + m) * 72 + 32 * ks + 8 * q];
        f16x8 b = *(const f16x8*)&WzB[((tsel * 2 + ks) * 64 + lane) * 8];
        za = __builtin_amdgcn_mfma_f32_16x16x32_f16(a, b, za, 0, 0, 0);
    }
    __builtin_amdgcn_s_setprio(0);
    {
        float bj = bzs[16 * tsel + m];
#pragma unroll
        for (int r = 0; r < 4; r++) {
            int node = 16 * rowg + 4 * q + r;
            float zv = za[r] + bj;
            Zh[node * 40 + 16 * tsel + m] = (f16)zv;
            if (row0 + node < n) z_out[(size_t)(row0 + node) * 32 + 16 * tsel + m] = zv;
        }
    }
    __syncthreads();

    // hd = relu(Zh @ Wd + bd) : wave handles t = 2*tsel + {0,1}
    f16x8 a2 = *(const f16x8*)&Zh[(16 * rowg + m) * 40 + 8 * q];
    __builtin_amdgcn_s_setprio(1);
#pragma unroll
    for (int tt = 0; tt < 2; tt++) {
        int t = 2 * tsel + tt;
        f32x4 zero = (f32x4){0.f, 0.f, 0.f, 0.f};
        f16x8 b = *(const f16x8*)&WdB[(t * 64 + lane) * 8];
        f32x4 hb = __builtin_amdgcn_mfma_f32_16x16x32_f16(a2, b, zero, 0, 0, 0);
        float bf = bds[16 * t + m];
#pragma unroll
        for (int r = 0; r < 4; r++) {
            int node = 16 * rowg + 4 * q + r;
            if (row0 + node < n)
                hd_ws[(size_t)(row0 + node) * 64 + 16 * t + m] = (f16)fmaxf(hb[r] + bf, 0.f);
        }
    }
    __builtin_amdgcn_s_setprio(0);

    if (tid < 64) {
        int node = tid;
        float pa = bcs[0], pb = bcs[1], pc = bcs[2];
        for (int k = 0; k < 32; k++) {
            float zv = (float)Zh[node * 40 + k];
            pa += zv * Wcs[k * 4 + 0];
            pb += zv * Wcs[k * 4 + 1];
            pc += zv * Wcs[k * 4 + 2];
        }
        if (row0 + node < n) {
            pred_out[(size_t)(row0 + node) * 3 + 0] = pa;
            pred_out[(size_t)(row0 + node) * 3 + 1] = pb;
            pred_out[(size_t)(row0 + node) * 3 + 2] = pc;
        }
    }
}

// ---------------- fused prop2 + GEMM5: 64 nodes per block, 8 waves, full-W staged ------

__global__ __launch_bounds__(512, 6) void k_decf(const f16* __restrict__ hd,
                                                 const int* __restrict__ row_ptr,
                                                 const int* __restrict__ ssorted,
                                                 const float* __restrict__ dinv,
                                                 const float* __restrict__ W,
                                                 const float* __restrict__ bias,
                                                 float* __restrict__ out, int n) {
    __shared__ __attribute__((aligned(16))) f16 WB[16 * 2 * 64 * 8];  // 32 KB
    __shared__ __attribute__((aligned(16))) f16 Ah[64 * 72];          // 9 KB
    __shared__ float bs[256];
    int tid = threadIdx.x;
    int row0 = blockIdx.x * 64;

    if (tid < 256) bs[tid] = bias[tid];

    for (int i = tid; i < 2048; i += 512) {
        int m = i & 15, q = (i >> 4) & 3, ks = (i >> 6) & 1, t = i >> 7;
        int col = 16 * t + m;
        int k0 = ks * 32 + q * 8;
        f16x8 v;
#pragma unroll
        for (int j = 0; j < 8; j++) v[j] = (f16)W[(k0 + j) * 256 + col];
        *(f16x8*)&WB[i * 8] = v;
    }

    int lane = tid & 63, wid = tid >> 6;  // wid 0..7
    int g = lane >> 4, fg = lane & 15;

    // gather phase: P(hd) rows -> Ah ; 32 node-slots per round, 2 rounds
    for (int r = 0; r < 2; r++) {
        int no = 32 * r + 4 * wid + g;
        int d = row0 + no;
        float vx = 0.f, vy = 0.f, vz = 0.f, vw = 0.f;
        if (d < n) {
            float dd = dinv[d];
            float ax, ay, az, aw;
            GCN_GATHER(hd, d, fg, ax, ay, az, aw, dd);
            vx = dd * ax; vy = dd * ay; vz = dd * az; vw = dd * aw;
        }
        half4 hv;
        hv.x = (f16)vx; hv.y = (f16)vy; hv.z = (f16)vz; hv.w = (f16)vw;
        *(half4*)&Ah[no * 72 + 4 * fg] = hv;
    }
    __syncthreads();

    int m = lane & 15, q = lane >> 4;
    int rowg = wid & 3, th = wid >> 2;

    f16x8 a0 = *(const f16x8*)&Ah[(16 * rowg + m) * 72 + 0 + 8 * q];
    f16x8 a1 = *(const f16x8*)&Ah[(16 * rowg + m) * 72 + 32 + 8 * q];

    int gr0 = row0 + 16 * rowg + 4 * q;
    bool full = (gr0 + 3 < n);
    __builtin_amdgcn_s_setprio(1);
#pragma unroll 4
    for (int tl = 0; tl < 8; tl++) {
        int t = 8 * th + tl;
        f32x4 acc = (f32x4){0.f, 0.f, 0.f, 0.f};
        f16x8 b0 = *(const f16x8*)&WB[((t * 2 + 0) * 64 + lane) * 8];
        acc = __builtin_amdgcn_mfma_f32_16x16x32_f16(a0, b0, acc, 0, 0, 0);
        f16x8 b1 = *(const f16x8*)&WB[((t * 2 + 1) * 64 + lane) * 8];
        acc = __builtin_amdgcn_mfma_f32_16x16x32_f16(a1, b1, acc, 0, 0, 0);
        float bf = bs[16 * t + m];
        if (full) {
#pragma unroll
            for (int r = 0; r < 4; r++)
                out[(size_t)(gr0 + r) * 256 + 16 * t + m] = acc[r] + bf;
        } else {
#pragma unroll
            for (int r = 0; r < 4; r++)
                if (gr0 + r < n) out[(size_t)(gr0 + r) * 256 + 16 * t + m] = acc[r] + bf;
        }
    }
    __builtin_amdgcn_s_setprio(0);
}

// ---------------- launch ----------------

extern "C" void kernel_launch(void* const* d_in, const int* in_sizes, int n_in,
                              void* d_out, int out_size, void* d_ws, size_t ws_size,
                              hipStream_t stream) {
    const float* x    = (const float*)d_in[0];
    const int*   ei   = (const int*)d_in[1];
    const float* Wenc = (const float*)d_in[3];
    const float* benc = (const float*)d_in[4];
    const float* Wz   = (const float*)d_in[5];
    const float* bz   = (const float*)d_in[6];
    const float* Wd   = (const float*)d_in[7];
    const float* bd   = (const float*)d_in[8];
    const float* Wdec = (const float*)d_in[9];
    const float* bdec = (const float*)d_in[10];
    const float* Wc   = (const float*)d_in[11];
    const float* bc   = (const float*)d_in[12];

    int n = in_sizes[0] / 256;
    int E = in_sizes[1] / 2;
    const int* src = ei;
    const int* dst = ei + E;

    int nbk = (n + BKT_SZ - 1) >> BKT_SH;
    int nbin = (E + EB - 1) / EB;

    char* w = (char*)d_ws;
    size_t off = 0;
    auto alloc = [&](size_t bytes) {
        void* p = w + off;
        off = (off + bytes + 255) & ~(size_t)255;
        return p;
    };
    int*      row_ptr = (int*)alloc(sizeof(int) * (n + 1));
    int*      ssorted = (int*)alloc(sizeof(int) * E);
    unsigned* ebuf    = (unsigned*)alloc(sizeof(unsigned) * (size_t)nbk * BCAP);
    float*    dinv    = (float*)alloc(sizeof(float) * n);
    int*      bcur    = (int*)alloc(sizeof(int) * 256);
    f16*      bufA    = (f16*)alloc(sizeof(f16) * (size_t)n * 64);  // h1pre
    f16*      bufB    = (f16*)alloc(sizeof(f16) * (size_t)n * 64);  // hd
    (void)ws_size; (void)n_in; (void)out_size;

    float* out_xr = (float*)d_out;
    float* out_z  = out_xr + (size_t)n * 256;
    float* out_p  = out_z + (size_t)n * 32;

    int tiles = (n + 63) / 64;
    int th = tiles / 2;

    hipMemsetAsync(bcur, 0, sizeof(int) * 256, stream);

    // phase 1: binning || gemm1 tiles [0, th)
    k_p1<<<dim3(nbin + th), dim3(256), 0, stream>>>(src, dst, E, bcur, ebuf,
                                                    x, Wenc, bufA, n, nbin, 0);
    // phase 2: per-bucket CSR || gemm1 tiles [th, tiles)
    k_p2<<<dim3(nbk + (tiles - th)), dim3(256), 0, stream>>>(ebuf, bcur, n, E, row_ptr, dinv, ssorted,
                                                             x, Wenc, bufA, nbk, th);

    // fused prop1 + middle: z (out), pred (out), hd -> bufB
    k_midf<<<dim3(tiles), dim3(512), 0, stream>>>(bufA, row_ptr, ssorted, dinv, benc,
                                                  Wz, bz, Wd, bd, Wc, bc,
                                                  bufB, out_z, out_p, n);

    // fused prop2 + decoder GEMM: x_recon = P(bufB) @ W_dec + b_dec
    k_decf<<<dim3(tiles), dim3(512), 0, stream>>>(bufB, row_ptr, ssorted, dinv,
                                                  Wdec, bdec, out_xr, n);
}